// Round 10
// baseline (667.597 us; speedup 1.0000x reference)
//
#include <hip/hip_runtime.h>

// GADBase guided anisotropic diffusion on MI355X — round 10.
// Persistent kernel + 2-step temporal blocking: R6's flag+barrier sync
// (measured ~4.8 us/exchange, protocol-invariant floor) paid 32x instead of
// 64x. Per round: step1 on the 9-px-extended region (interior via R6 fp32
// register conductances + 2-shuffle cell sums; ring via item loop with
// global L2-resident conductance reads + LDS atomics), ratios, step2 on the
// interior (R6 pattern, ratio applied on LDS read), publish 9-wide border
// strips to 8 neighbors (corners via diagonal row-strips), stage incoming
// ring. LDS ~50KB -> 2 blocks/CU guaranteed co-resident (512 blocks).

#define BB 2
#define HH 1024
#define WW 1024
#define NPIX (HH * WW)
#define CVN (1023 * 1024)
#define SHW (128 * 128)
#define LL 0.24f
#define KK2 (0.03f * 0.03f)
#define EPSF 1e-8f
#define DEPSF 0.1f
#define NPRE 64
#define NB 512
#define TPB 256
#define NROUND 32

#define PW 1056            // padded plane width (guard 16)
#define PG 16
#define PN (PW * PW)
#define Q(y, x) (((y) + PG) * PW + ((x) + PG))

#define SYS_LDU(p)    __hip_atomic_load((p), __ATOMIC_RELAXED, __HIP_MEMORY_SCOPE_SYSTEM)
#define SYS_STU(p, v) __hip_atomic_store((p), (v), __ATOMIC_RELAXED, __HIP_MEMORY_SCOPE_SYSTEM)
#define SYS_LDF(p)    __hip_atomic_load((p), __ATOMIC_RELAXED, __HIP_MEMORY_SCOPE_SYSTEM)
#define SYS_STF(p, v) __hip_atomic_store((p), (v), __ATOMIC_RELAXED, __HIP_MEMORY_SCOPE_SYSTEM)

__global__ void zero_kernel(float4* __restrict__ p) {
    size_t i = (size_t)blockIdx.x * TPB + threadIdx.x;
    p[i] = make_float4(0.f, 0.f, 0.f, 0.f);
}

__global__ void setup_kernel(const float* __restrict__ src, float* __restrict__ shiftOut,
                             unsigned* __restrict__ flags) {
    int tid = threadIdx.x;
    for (int i = tid; i < NB * 16; i += TPB) flags[i] = 0u;
    float m = 1e30f;
    for (int i = tid; i < BB * SHW; i += TPB) m = fminf(m, src[i]);
    for (int off = 32; off > 0; off >>= 1) m = fminf(m, __shfl_down(m, off));
    __shared__ float sm[4];
    if ((tid & 63) == 0) sm[tid >> 6] = m;
    __syncthreads();
    if (tid == 0) {
        float mm = fminf(fminf(sm[0], sm[1]), fminf(sm[2], sm[3]));
        shiftOut[0] = (mm <= DEPSF) ? DEPSF : 0.0f;
    }
}

__global__ void init_kernel(const float* __restrict__ guide, const float* __restrict__ yb,
                            const float* __restrict__ shiftPtr, float* __restrict__ imA,
                            float* __restrict__ cv_out, float* __restrict__ ch_out,
                            float* __restrict__ cvq, float* __restrict__ chq) {
    int idx = blockIdx.x * blockDim.x + threadIdx.x;
    if (idx >= BB * NPIX) return;
    int b = idx >> 20;
    int p = idx & (NPIX - 1);
    int y = p >> 10;
    int x = p & 1023;
    const float* gb = guide + (size_t)b * 3 * NPIX;
    const float* yBb = yb + (size_t)b * NPIX;
    float c0 = yBb[p];
    imA[(size_t)b * PN + Q(y, x)] = c0 + shiftPtr[0];
    if (y < HH - 1) {
        float d = fabsf(gb[p + WW] - gb[p])
                + fabsf(gb[NPIX + p + WW] - gb[NPIX + p])
                + fabsf(gb[2 * NPIX + p + WW] - gb[2 * NPIX + p])
                + fabsf(yBb[p + WW] - c0);
        d *= 0.25f;
        float v = 1.0f / (1.0f + (d * d) / KK2);
        cv_out[(size_t)b * CVN + y * WW + x] = v;
        cvq[(size_t)b * PN + Q(y, x)] = v;     // guards pre-zeroed
    }
    if (x < WW - 1) {
        float d = fabsf(gb[p + 1] - gb[p])
                + fabsf(gb[NPIX + p + 1] - gb[NPIX + p])
                + fabsf(gb[2 * NPIX + p + 1] - gb[2 * NPIX + p])
                + fabsf(yBb[p + 1] - c0);
        d *= 0.25f;
        float v = 1.0f / (1.0f + (d * d) / KK2);
        ch_out[(size_t)b * CVN + y * 1023 + x] = v;
        chq[(size_t)b * PN + Q(y, x)] = v;
    }
}

// LDS tiles. cur: rows -9..40, cols -12..139 (stride 152, +12 offset).
// nxt: rows -1..32, cols -4..131 (stride 136, +4 offset).
#define CUR(y, x) cur[((y) + 9) * 152 + (x) + 12]
#define NXT(y, x) nxt[((y) + 1) * 136 + (x) + 4]

__device__ inline bool fok(const unsigned* p, unsigned t) {
    return (p == nullptr) || (SYS_LDU(p) >= t);
}
__device__ inline float fget(const float4& v, int e) {
    return e == 0 ? v.x : (e == 1 ? v.y : (e == 2 ? v.z : v.w));
}

__launch_bounds__(TPB, 2)
__global__ void persist_kernel(const float* __restrict__ imA, float* __restrict__ out,
                               const float* __restrict__ cvq, const float* __restrict__ chq,
                               const float* __restrict__ src, const float* __restrict__ mask,
                               const float* __restrict__ shiftPtr,
                               float* __restrict__ bufT, float* __restrict__ bufB,
                               float* __restrict__ bufL, float* __restrict__ bufR,
                               unsigned* __restrict__ flags) {
    __shared__ __align__(16) float cur[50 * 152];
    __shared__ __align__(16) float nxt[34 * 136];
    __shared__ float cellSum[108];
    __shared__ float ratioS[108];

    int blk = blockIdx.x;
    int b = blk >> 8;
    int rr = blk & 255;
    int tileY = rr >> 3;             // 0..31
    int tileX = rr & 7;              // 0..7
    int tid = threadIdx.x;
    int cyL = tid >> 5;
    int g = tid & 31;
    int lx0 = g * 4, ly0 = cyL * 4;
    int ty0 = tileY * 32, tx0 = tileX * 128;
    int gx = tx0 + lx0, gy = ty0 + ly0;

    const float* imb = imA + (size_t)b * PN;
    const float* cvb = cvq + (size_t)b * PN;
    const float* chb = chq + (size_t)b * PN;
    float shift = shiftPtr[0];

    // fp32 conductances for the interior (both steps; time-invariant)
    float4 cvR[5], chR[4];
    float hmR[4];
#pragma unroll
    for (int j = 0; j < 5; ++j) cvR[j] = *(const float4*)&cvb[Q(gy - 1 + j, gx)];
#pragma unroll
    for (int k = 0; k < 4; ++k) {
        chR[k] = *(const float4*)&chb[Q(gy + k, gx)];
        hmR[k] = chb[Q(gy + k, gx - 1)];
    }
    int sidx2 = b * SHW + ((ty0 >> 3) + (cyL >> 1)) * 128 + (tx0 >> 3) + (g >> 1);
    float sval = src[sidx2] + shift;
    bool masked = mask[sidx2] < 0.5f;

    // ring-cell src/mask (6x18 grid incl. -1 ring), cached in registers
    float rS = 0.f; bool rM = true;
    if (tid < 108) {
        int cr = tid / 18, cc = tid - cr * 18;
        int gyc = (ty0 >> 3) + cr - 1;
        int gxc = (tx0 >> 3) + cc - 1;
        gyc = gyc < 0 ? 0 : (gyc > 127 ? 127 : gyc);
        gxc = gxc < 0 ? 0 : (gxc > 127 ? 127 : gxc);
        int si = b * SHW + gyc * 128 + gxc;
        rS = src[si] + shift;
        rM = mask[si] < 0.5f;
        cellSum[tid] = 0.f;
    }

    // initial cur fill: 50 rows x 38 quads from padded init image
#pragma unroll
    for (int j = 0; j < 8; ++j) {
        int i = j * TPB + tid;
        if (i < 1900) {
            int r2 = i / 38, c4 = i - r2 * 38;
            *(float4*)&cur[r2 * 152 + c4 * 4] =
                *(const float4*)&imb[Q(ty0 + r2 - 9, tx0 + c4 * 4 - 12)];
        }
    }

    // neighbor flags (nullable)
    const unsigned* f0 = (tileY > 0) ? &flags[(blk - 8) * 16] : nullptr;
    const unsigned* f1 = (tileY > 0 && tileX > 0) ? &flags[(blk - 9) * 16] : nullptr;
    const unsigned* f2 = (tileY > 0 && tileX < 7) ? &flags[(blk - 7) * 16] : nullptr;
    const unsigned* f3 = (tileX > 0) ? &flags[(blk - 1) * 16] : nullptr;
    const unsigned* f4 = (tileX < 7) ? &flags[(blk + 1) * 16] : nullptr;
    const unsigned* f5 = (tileY < 31) ? &flags[(blk + 8) * 16] : nullptr;
    const unsigned* f6 = (tileY < 31 && tileX > 0) ? &flags[(blk + 7) * 16] : nullptr;
    const unsigned* f7 = (tileY < 31 && tileX < 7) ? &flags[(blk + 9) * 16] : nullptr;

    __syncthreads();

    for (int t = 0; t < NROUND; ++t) {
        // ---- A1: step1 on interior (fp32 regs), values -> nxt, sums via shfl ----
        {
            float4 rUp = *(float4*)&CUR(ly0 - 1, lx0);
            float4 rC  = *(float4*)&CUR(ly0, lx0);
            float cs = 0.f;
#pragma unroll
            for (int k = 0; k < 4; ++k) {
                int y = ly0 + k;
                float4 rDn = *(float4*)&CUR(y + 1, lx0);
                float4 cu = cvR[k], cd = cvR[k + 1], h4 = chR[k];
                float xl = CUR(y, lx0 - 1);
                float xr = CUR(y, lx0 + 4);
                float hm = hmR[k];
                float4 a;
                a.x = rC.x + LL * (cd.x * (rDn.x - rC.x) - cu.x * (rC.x - rUp.x)
                                 + h4.x * (rC.y - rC.x) - hm   * (rC.x - xl));
                a.y = rC.y + LL * (cd.y * (rDn.y - rC.y) - cu.y * (rC.y - rUp.y)
                                 + h4.y * (rC.z - rC.y) - h4.x * (rC.y - rC.x));
                a.z = rC.z + LL * (cd.z * (rDn.z - rC.z) - cu.z * (rC.z - rUp.z)
                                 + h4.z * (rC.w - rC.z) - h4.y * (rC.z - rC.y));
                a.w = rC.w + LL * (cd.w * (rDn.w - rC.w) - cu.w * (rC.w - rUp.w)
                                 + h4.w * (xr   - rC.w) - h4.z * (rC.w - rC.z));
                *(float4*)&NXT(y, lx0) = a;
                cs += a.x + a.y + a.z + a.w;
                rUp = rC; rC = rDn;
            }
            cs += __shfl_xor(cs, 1);
            cs += __shfl_xor(cs, 32);
            if ((tid & 33) == 0)
                cellSum[(1 + (cyL >> 1)) * 18 + 1 + (g >> 1)] = cs;
        }
        // ---- A2: step1 on the ring (global L2-resident conductances) ----
#pragma unroll
        for (int j = 0; j < 7; ++j) {
            int i = j * TPB + tid;
            if (i < 1728) {
                int r2 = i / 36, c4 = i - r2 * 36;
                int y = r2 - 8, c0 = c4 * 4 - 8;
                if (!(y >= 0 && y <= 31 && c0 >= 0 && c0 <= 124)) {
                    float4 up = *(float4*)&CUR(y - 1, c0);
                    float4 cc = *(float4*)&CUR(y, c0);
                    float4 dn = *(float4*)&CUR(y + 1, c0);
                    float xl = CUR(y, c0 - 1);
                    float xr = CUR(y, c0 + 4);
                    int ay = ty0 + y, ax = tx0 + c0;
                    float4 cu = *(const float4*)&cvb[Q(ay - 1, ax)];
                    float4 cd = *(const float4*)&cvb[Q(ay, ax)];
                    float4 h4 = *(const float4*)&chb[Q(ay, ax)];
                    float hm = chb[Q(ay, ax - 1)];
                    float4 a;
                    a.x = cc.x + LL * (cd.x * (dn.x - cc.x) - cu.x * (cc.x - up.x)
                                     + h4.x * (cc.y - cc.x) - hm   * (cc.x - xl));
                    a.y = cc.y + LL * (cd.y * (dn.y - cc.y) - cu.y * (cc.y - up.y)
                                     + h4.y * (cc.z - cc.y) - h4.x * (cc.y - cc.x));
                    a.z = cc.z + LL * (cd.z * (dn.z - cc.z) - cu.z * (cc.z - up.z)
                                     + h4.z * (cc.w - cc.z) - h4.y * (cc.z - cc.y));
                    a.w = cc.w + LL * (cd.w * (dn.w - cc.w) - cu.w * (cc.w - up.w)
                                     + h4.w * (xr   - cc.w) - h4.z * (cc.w - cc.z));
                    atomicAdd(&cellSum[((y + 8) >> 3) * 18 + ((c0 + 8) >> 3)],
                              a.x + a.y + a.z + a.w);
                    if (y >= -1 && y <= 32 && c0 >= -4 && c0 <= 128)
                        *(float4*)&NXT(y, c0) = a;
                }
            }
        }
        __syncthreads();   // b1

        if (tid < 108) {
            ratioS[tid] = rM ? 1.0f : rS / (cellSum[tid] * (1.0f / 64.0f) + EPSF);
            cellSum[tid] = 0.f;
        }
        __syncthreads();   // b2

        // ---- C: step2 on interior, ratios applied on nxt reads ----
        float4 nv[4];
        float csum = 0.f;
        {
            int cc = (lx0 + 8) >> 3;
            float4 rUp = *(float4*)&NXT(ly0 - 1, lx0);
            { float rt = ratioS[((ly0 + 7) >> 3) * 18 + cc];
              rUp.x *= rt; rUp.y *= rt; rUp.z *= rt; rUp.w *= rt; }
            float4 rC = *(float4*)&NXT(ly0, lx0);
            { float rt = ratioS[((ly0 + 8) >> 3) * 18 + cc];
              rC.x *= rt; rC.y *= rt; rC.z *= rt; rC.w *= rt; }
#pragma unroll
            for (int k = 0; k < 4; ++k) {
                int y = ly0 + k;
                float4 rDn = *(float4*)&NXT(y + 1, lx0);
                { float rt = ratioS[((y + 9) >> 3) * 18 + cc];
                  rDn.x *= rt; rDn.y *= rt; rDn.z *= rt; rDn.w *= rt; }
                float4 cu = cvR[k], cd = cvR[k + 1], h4 = chR[k];
                float hm = hmR[k];
                float xl = __shfl_up(rC.w, 1);
                float xr = __shfl_down(rC.x, 1);
                if (g == 0)  xl = NXT(y, -1) * ratioS[((y + 8) >> 3) * 18 + 0];
                if (g == 31) xr = NXT(y, 128) * ratioS[((y + 8) >> 3) * 18 + 17];
                float4 a;
                a.x = rC.x + LL * (cd.x * (rDn.x - rC.x) - cu.x * (rC.x - rUp.x)
                                 + h4.x * (rC.y - rC.x) - hm   * (rC.x - xl));
                a.y = rC.y + LL * (cd.y * (rDn.y - rC.y) - cu.y * (rC.y - rUp.y)
                                 + h4.y * (rC.z - rC.y) - h4.x * (rC.y - rC.x));
                a.z = rC.z + LL * (cd.z * (rDn.z - rC.z) - cu.z * (rC.z - rUp.z)
                                 + h4.z * (rC.w - rC.z) - h4.y * (rC.z - rC.y));
                a.w = rC.w + LL * (cd.w * (rDn.w - rC.w) - cu.w * (rC.w - rUp.w)
                                 + h4.w * (xr   - rC.w) - h4.z * (rC.w - rC.z));
                nv[k] = a;
                csum += a.x + a.y + a.z + a.w;
                rUp = rC; rC = rDn;
            }
        }
        csum += __shfl_xor(csum, 1);
        csum += __shfl_xor(csum, 32);
        float ratio2 = masked ? 1.0f : sval / (csum * (1.0f / 64.0f) + EPSF);

        if (t == NROUND - 1) {
            float* ob = out + (size_t)b * NPIX;
#pragma unroll
            for (int k = 0; k < 4; ++k) {
                float4 v = nv[k];
                v.x = v.x * ratio2 - shift; v.y = v.y * ratio2 - shift;
                v.z = v.z * ratio2 - shift; v.w = v.w * ratio2 - shift;
                *(float4*)&ob[(size_t)(gy + k) * WW + gx] = v;
            }
        } else {
#pragma unroll
            for (int k = 0; k < 4; ++k) {
                nv[k].x *= ratio2; nv[k].y *= ratio2;
                nv[k].z *= ratio2; nv[k].w *= ratio2;
            }
            int p1 = (t + 1) & 1;
            // ---- D: publish 9-wide border strips (system scope) ----
#pragma unroll
            for (int k = 0; k < 4; ++k) {
                int row = ly0 + k;
                if (row < 9) {
                    float* p = &bufT[(((size_t)p1 * NB + blk) * 9 + row) * 128 + lx0];
                    SYS_STF(p + 0, nv[k].x); SYS_STF(p + 1, nv[k].y);
                    SYS_STF(p + 2, nv[k].z); SYS_STF(p + 3, nv[k].w);
                }
                if (row >= 23) {
                    float* p = &bufB[(((size_t)p1 * NB + blk) * 9 + row - 23) * 128 + lx0];
                    SYS_STF(p + 0, nv[k].x); SYS_STF(p + 1, nv[k].y);
                    SYS_STF(p + 2, nv[k].z); SYS_STF(p + 3, nv[k].w);
                }
                if (g < 3) {
#pragma unroll
                    for (int e = 0; e < 4; ++e) {
                        int col = lx0 + e;
                        if (col < 9)
                            SYS_STF(&bufL[(((size_t)p1 * NB + blk) * 32 + row) * 9 + col],
                                    fget(nv[k], e));
                    }
                }
                if (g >= 29) {
#pragma unroll
                    for (int e = 0; e < 4; ++e) {
                        int col = lx0 + e;
                        if (col >= 119)
                            SYS_STF(&bufR[(((size_t)p1 * NB + blk) * 32 + row) * 9 + col - 119],
                                    fget(nv[k], e));
                    }
                }
                // E: interior of new state into cur
                *(float4*)&CUR(row, lx0) = nv[k];
            }
            __syncthreads();   // b3: all publish stores drained (vmcnt before barrier)
            if (tid == 0) {
                __builtin_amdgcn_s_waitcnt(0);
                SYS_STU(&flags[blk * 16], (unsigned)(t + 1));
            }
            // ---- F: wait on <=8 neighbor flags ----
            unsigned tgt = (unsigned)(t + 1);
            for (;;) {
                if (fok(f0, tgt) && fok(f1, tgt) && fok(f2, tgt) && fok(f3, tgt) &&
                    fok(f4, tgt) && fok(f5, tgt) && fok(f6, tgt) && fok(f7, tgt)) break;
                __builtin_amdgcn_s_sleep(1);
            }
            // ---- G: stage 9-px ring into cur ----
            if (tileY > 0) {
                for (int i = tid; i < 1314; i += TPB) {
                    int y = i / 146 - 9, xx = i % 146 - 9;
                    float v; bool ok = true;
                    if (xx < 0) {
                        if (tileX > 0)
                            v = SYS_LDF(&bufB[(((size_t)p1 * NB + blk - 9) * 9 + y + 9) * 128 + xx + 128]);
                        else ok = false;
                    } else if (xx < 128) {
                        v = SYS_LDF(&bufB[(((size_t)p1 * NB + blk - 8) * 9 + y + 9) * 128 + xx]);
                    } else {
                        if (tileX < 7)
                            v = SYS_LDF(&bufB[(((size_t)p1 * NB + blk - 7) * 9 + y + 9) * 128 + xx - 128]);
                        else ok = false;
                    }
                    if (ok) CUR(y, xx) = v;
                }
            }
            if (tileY < 31) {
                for (int i = tid; i < 1314; i += TPB) {
                    int y = i / 146 + 32, xx = i % 146 - 9;
                    float v; bool ok = true;
                    if (xx < 0) {
                        if (tileX > 0)
                            v = SYS_LDF(&bufT[(((size_t)p1 * NB + blk + 7) * 9 + y - 32) * 128 + xx + 128]);
                        else ok = false;
                    } else if (xx < 128) {
                        v = SYS_LDF(&bufT[(((size_t)p1 * NB + blk + 8) * 9 + y - 32) * 128 + xx]);
                    } else {
                        if (tileX < 7)
                            v = SYS_LDF(&bufT[(((size_t)p1 * NB + blk + 9) * 9 + y - 32) * 128 + xx - 128]);
                        else ok = false;
                    }
                    if (ok) CUR(y, xx) = v;
                }
            }
            if (tileX > 0) {
                for (int i = tid; i < 288; i += TPB) {
                    int row = i / 9, c = i - row * 9;
                    CUR(row, c - 9) =
                        SYS_LDF(&bufR[(((size_t)p1 * NB + blk - 1) * 32 + row) * 9 + c]);
                }
            }
            if (tileX < 7) {
                for (int i = tid; i < 288; i += TPB) {
                    int row = i / 9, c = i - row * 9;
                    CUR(row, 128 + c) =
                        SYS_LDF(&bufL[(((size_t)p1 * NB + blk + 1) * 32 + row) * 9 + c]);
                }
            }
            __syncthreads();   // b4
        }
    }
}

extern "C" void kernel_launch(void* const* d_in, const int* in_sizes, int n_in,
                              void* d_out, int out_size, void* d_ws, size_t ws_size,
                              hipStream_t stream) {
    const float* guide = (const float*)d_in[0];
    const float* yb    = (const float*)d_in[1];
    const float* src   = (const float*)d_in[2];
    const float* mask  = (const float*)d_in[3];

    float* out    = (float*)d_out;
    float* out_cv = out + (size_t)BB * NPIX;
    float* out_ch = out_cv + (size_t)BB * CVN;

    float* wsf = (float*)d_ws;
    float* shift = wsf;                                   // [256]
    unsigned* flags = (unsigned*)(wsf + 256);             // 512*16
    float* imA = wsf + 256 + NB * 16;                     // 2 padded planes
    float* cvq = imA + (size_t)BB * PN;                   // 2 padded planes (zeroed)
    float* chq = cvq + (size_t)BB * PN;                   // 2 padded planes (zeroed)
    float* bufT = chq + (size_t)BB * PN;                  // 2par x 512 x 9 x 128
    float* bufB = bufT + (size_t)2 * NB * 9 * 128;
    float* bufL = bufB + (size_t)2 * NB * 9 * 128;        // 2par x 512 x 32 x 9
    float* bufR = bufL + (size_t)2 * NB * 32 * 9;

    // zero cvq+chq (contiguous 4*PN floats = PN float4)
    zero_kernel<<<PN / TPB, TPB, 0, stream>>>((float4*)cvq);
    setup_kernel<<<1, TPB, 0, stream>>>(src, shift, flags);
    init_kernel<<<(BB * NPIX) / TPB, TPB, 0, stream>>>(guide, yb, shift, imA,
                                                       out_cv, out_ch, cvq, chq);

    persist_kernel<<<NB, TPB, 0, stream>>>(imA, out, cvq, chq, src, mask, shift,
                                           bufT, bufB, bufL, bufR, flags);
}

// Round 11
// 308.801 us; speedup vs baseline: 2.1619x; 2.1619x over previous
//
#include <hip/hip_runtime.h>

// GADBase guided anisotropic diffusion on MI355X — round 11.
// Best-known skeleton (R6, 338us persist) + three fixes derived from the
// R8/R10 write-amplification post-mortem:
//  1) publishes are packed (value,tag) pairs via global_store_dwordx4 sc0 sc1
//     — lane-contiguous full-line uncached writes (no 4x amplification).
//  2) tagged-word sync (no flags, no vmcnt drain): consumer polls the data
//     words for tag == state index. Publisher and poller of each edge are
//     the SAME thread, so parity-slot overwrite safety is per-thread program
//     order; all waits reference earlier iterations -> deadlock-free.
//  3) halos live in REGISTERS (each halo word is consumed only by its
//     staging thread) + double-buffered 32x128 LDS tile -> ONE barrier/step.

#define BB 2
#define HH 1024
#define WW 1024
#define NPIX (HH * WW)
#define CVN (1023 * 1024)
#define CVPN (1025 * 1024)
#define SHW (128 * 128)
#define LL 0.24f
#define KK2 (0.03f * 0.03f)
#define EPSF 1e-8f
#define DEPSF 0.1f
#define NPRE 64
#define NB 512            // 2 blocks/CU on 256 CUs — co-resident
#define TPB 256

typedef unsigned long long u64;
typedef unsigned int uint4v __attribute__((ext_vector_type(4)));
#define SYS_LD64(p) __hip_atomic_load((p), __ATOMIC_RELAXED, __HIP_MEMORY_SCOPE_SYSTEM)

#define ROWPAR ((size_t)NB * 2 * 128)   // u64s per parity plane (row buffers)
#define COLPAR ((size_t)NB * 2 * 32)

__global__ void setup_kernel(const float* __restrict__ src, float* __restrict__ shiftOut) {
    int tid = threadIdx.x;
    float m = 1e30f;
    for (int i = tid; i < BB * SHW; i += TPB) m = fminf(m, src[i]);
    for (int off = 32; off > 0; off >>= 1) m = fminf(m, __shfl_down(m, off));
    __shared__ float sm[4];
    if ((tid & 63) == 0) sm[tid >> 6] = m;
    __syncthreads();
    if (tid == 0) {
        float mm = fminf(fminf(sm[0], sm[1]), fminf(sm[2], sm[3]));
        shiftOut[0] = (mm <= DEPSF) ? DEPSF : 0.0f;
    }
}

__global__ void init_kernel(const float* __restrict__ guide, const float* __restrict__ yb,
                            const float* __restrict__ shiftPtr, float* __restrict__ img0,
                            float* __restrict__ cv_out, float* __restrict__ ch_out,
                            float* __restrict__ cvp, float* __restrict__ chp) {
    int idx = blockIdx.x * blockDim.x + threadIdx.x;
    if (idx >= BB * NPIX) return;
    int b = idx >> 20;
    int p = idx & (NPIX - 1);
    int y = p >> 10;
    int x = p & 1023;
    const float* gb = guide + (size_t)b * 3 * NPIX;
    const float* yBb = yb + (size_t)b * NPIX;
    float c0 = yBb[p];
    img0[(size_t)b * NPIX + p] = c0 + shiftPtr[0];
    // shift cancels in finite diffs -> cv/ch from raw y_bicubic.
    float* cvpb = cvp + (size_t)b * CVPN;
    float* chpb = chp + (size_t)b * NPIX;
    if (y < HH - 1) {
        float d = fabsf(gb[p + WW] - gb[p])
                + fabsf(gb[NPIX + p + WW] - gb[NPIX + p])
                + fabsf(gb[2 * NPIX + p + WW] - gb[2 * NPIX + p])
                + fabsf(yBb[p + WW] - c0);
        d *= 0.25f;
        float v = 1.0f / (1.0f + (d * d) / KK2);
        cv_out[(size_t)b * CVN + y * WW + x] = v;
        cvpb[(y + 1) * WW + x] = v;           // padded: row r holds cv[r-1]
    } else {
        cvpb[x] = 0.f;
        cvpb[1024 * WW + x] = 0.f;
    }
    if (x < WW - 1) {
        float d = fabsf(gb[p + 1] - gb[p])
                + fabsf(gb[NPIX + p + 1] - gb[NPIX + p])
                + fabsf(gb[2 * NPIX + p + 1] - gb[2 * NPIX + p])
                + fabsf(yBb[p + 1] - c0);
        d *= 0.25f;
        float v = 1.0f / (1.0f + (d * d) / KK2);
        ch_out[(size_t)b * CVN + y * 1023 + x] = v;
        chpb[y * WW + x] = v;                 // padded stride-1024, col 1023 = 0
    } else {
        chpb[y * WW + 1023] = 0.f;
    }
}

// 16B packed publish: two (value,tag) u64s, uncached (sc0 sc1), fire-and-forget.
__device__ inline void pub2(u64* p, float v0, float v1, unsigned s) {
    uint4v q;
    q.x = __float_as_uint(v0); q.y = s;
    q.z = __float_as_uint(v1); q.w = s;
    asm volatile("global_store_dwordx4 %0, %1, off sc0 sc1"
                 :: "v"(p), "v"(q) : "memory");
}

// Poll 4 tagged u64s until all carry tag s; return the 4 values.
__device__ inline float4 poll4(const u64* p, unsigned s) {
    u64 a0, a1, a2, a3;
    for (;;) {
        a0 = SYS_LD64(p + 0); a1 = SYS_LD64(p + 1);
        a2 = SYS_LD64(p + 2); a3 = SYS_LD64(p + 3);
        if ((unsigned)(a0 >> 32) == s && (unsigned)(a1 >> 32) == s &&
            (unsigned)(a2 >> 32) == s && (unsigned)(a3 >> 32) == s) break;
        __builtin_amdgcn_s_sleep(1);
    }
    return make_float4(__uint_as_float((unsigned)a0), __uint_as_float((unsigned)a1),
                       __uint_as_float((unsigned)a2), __uint_as_float((unsigned)a3));
}

__launch_bounds__(TPB, 2)
__global__ void persist_kernel(const float* __restrict__ img0, float* __restrict__ out,
                               const float* __restrict__ cvp, const float* __restrict__ chp,
                               const float* __restrict__ src, const float* __restrict__ mask,
                               const float* __restrict__ shiftPtr,
                               u64* __restrict__ bufRow, u64* __restrict__ bufCol) {
    __shared__ float tile[2][32 * 128];
    int blk = blockIdx.x;
    int b = blk >> 8;
    int r = blk & 255;
    int tileY = r >> 3;          // 0..31
    int tileX = r & 7;           // 0..7
    int tid = threadIdx.x;
    int cyL = tid >> 5;          // 0..7
    int g = tid & 31;            // 0..31
    int lx0 = g * 4;
    int ly0 = cyL * 4;
    int gx = tileX * 128 + lx0;
    int gy = tileY * 32 + ly0;

    const float* im0 = img0 + (size_t)b * NPIX;
    const float* cvpb = cvp + (size_t)b * CVPN;
    const float* chpb = chp + (size_t)b * NPIX;
    float shift = shiftPtr[0];

    // conductances resident in registers for all 64 steps
    float4 cvR[5], chR[4];
    float hmR[4];
#pragma unroll
    for (int j = 0; j < 5; ++j)
        cvR[j] = *(const float4*)(cvpb + (size_t)(gy + j) * WW + gx);
#pragma unroll
    for (int k = 0; k < 4; ++k) {
        chR[k] = *(const float4*)(chpb + (size_t)(gy + k) * WW + gx);
        hmR[k] = (gx > 0) ? chpb[(size_t)(gy + k) * WW + gx - 1] : 0.f;
    }
    int sidx = b * SHW + (tileY * 4 + (cyL >> 1)) * 128 + tileX * 16 + (g >> 1);
    float sval = src[sidx] + shift;
    bool masked = mask[sidx] < 0.5f;

    // role predicates (each edge's publisher == its poller thread)
    bool upAct = (cyL == 0 && tileY > 0);
    bool dnAct = (cyL == 7 && tileY < 31);
    bool lAct  = (g == 0  && tileX > 0);
    bool rAct  = (g == 31 && tileX < 7);

    float* cur = &tile[0][0];
    float* nxt = &tile[1][0];

    // initial LDS interior + state-0 halo registers (0 past image edges:
    // matching conductance is 0 so the value is never used)
#pragma unroll
    for (int k = 0; k < 4; ++k)
        *(float4*)&cur[(ly0 + k) * 128 + lx0] =
            *(const float4*)(im0 + (size_t)(gy + k) * WW + gx);
    float4 z4 = make_float4(0.f, 0.f, 0.f, 0.f);
    float4 hUp = z4, hDn = z4;
    float xlR[4] = {0.f, 0.f, 0.f, 0.f}, xrR[4] = {0.f, 0.f, 0.f, 0.f};
    if (upAct) hUp = *(const float4*)(im0 + (size_t)(gy - 1) * WW + gx);
    if (dnAct) hDn = *(const float4*)(im0 + (size_t)(gy + 4) * WW + gx);
    if (lAct) {
#pragma unroll
        for (int k = 0; k < 4; ++k) xlR[k] = im0[(size_t)(gy + k) * WW + gx - 1];
    }
    if (rAct) {
#pragma unroll
        for (int k = 0; k < 4; ++k) xrR[k] = im0[(size_t)(gy + k) * WW + gx + 4];
    }
    __syncthreads();

    float4 nv[4];
    for (int t = 0; t < NPRE; ++t) {
        // ---- A: poll halos of state t into registers (t>=1) ----
        if (t > 0) {
            unsigned s = (unsigned)t;
            size_t rOff = (s & 1) ? ROWPAR : 0;
            size_t cOff = (s & 1) ? COLPAR : 0;
            if (upAct)
                hUp = poll4(&bufRow[rOff + (((size_t)blk - 8) * 2 + 1) * 128 + lx0], s);
            if (dnAct)
                hDn = poll4(&bufRow[rOff + (((size_t)blk + 8) * 2 + 0) * 128 + lx0], s);
            if (lAct) {
                float4 c = poll4(&bufCol[cOff + (((size_t)blk - 1) * 2 + 1) * 32 + ly0], s);
                xlR[0] = c.x; xlR[1] = c.y; xlR[2] = c.z; xlR[3] = c.w;
            }
            if (rAct) {
                float4 c = poll4(&bufCol[cOff + (((size_t)blk + 1) * 2 + 0) * 32 + ly0], s);
                xrR[0] = c.x; xrR[1] = c.y; xrR[2] = c.z; xrR[3] = c.w;
            }
        }

        // ---- B: diffuse + adjust, state t -> nv = state t+1 ----
        float4 rUp = (cyL == 0) ? hUp : *(float4*)&cur[(ly0 - 1) * 128 + lx0];
        float4 rC  = *(float4*)&cur[ly0 * 128 + lx0];
        float csum = 0.f;
#pragma unroll
        for (int k = 0; k < 4; ++k) {
            float4 rDn = (k == 3 && cyL == 7) ? hDn
                       : *(float4*)&cur[(ly0 + 1 + k) * 128 + lx0];
            float4 cu = cvR[k], cd = cvR[k + 1], h4 = chR[k];
            float xl = __shfl_up(rC.w, 1);
            float xr = __shfl_down(rC.x, 1);
            float hm = hmR[k];
            if (g == 0)  xl = xlR[k];
            if (g == 31) xr = xrR[k];
            float4 a;
            a.x = rC.x + LL * (cd.x * (rDn.x - rC.x) - cu.x * (rC.x - rUp.x)
                             + h4.x * (rC.y - rC.x) - hm   * (rC.x - xl));
            a.y = rC.y + LL * (cd.y * (rDn.y - rC.y) - cu.y * (rC.y - rUp.y)
                             + h4.y * (rC.z - rC.y) - h4.x * (rC.y - rC.x));
            a.z = rC.z + LL * (cd.z * (rDn.z - rC.z) - cu.z * (rC.z - rUp.z)
                             + h4.z * (rC.w - rC.z) - h4.y * (rC.z - rC.y));
            a.w = rC.w + LL * (cd.w * (rDn.w - rC.w) - cu.w * (rC.w - rUp.w)
                             + h4.w * (xr   - rC.w) - h4.z * (rC.w - rC.z));
            nv[k] = a;
            csum += a.x + a.y + a.z + a.w;
            rUp = rC; rC = rDn;
        }
        csum += __shfl_xor(csum, 1);
        csum += __shfl_xor(csum, 32);   // 8x8 cell = lanes {tid,tid^1,tid^32,tid^33}
        float ratio = masked ? 1.0f : sval / (csum * (1.0f / 64.0f) + EPSF);

        if (t == NPRE - 1) {
            float* ob = out + (size_t)b * NPIX;
#pragma unroll
            for (int k = 0; k < 4; ++k) {
                float4 v = nv[k];
                v.x = v.x * ratio - shift; v.y = v.y * ratio - shift;
                v.z = v.z * ratio - shift; v.w = v.w * ratio - shift;
                *(float4*)(ob + (size_t)(gy + k) * WW + gx) = v;
            }
            break;
        }
#pragma unroll
        for (int k = 0; k < 4; ++k) {
            nv[k].x *= ratio; nv[k].y *= ratio; nv[k].z *= ratio; nv[k].w *= ratio;
        }

        // ---- C: publish my edges tagged s2 (packed dwordx4, uncached) ----
        unsigned s2 = (unsigned)(t + 1);
        size_t rOff2 = (s2 & 1) ? ROWPAR : 0;
        size_t cOff2 = (s2 & 1) ? COLPAR : 0;
        if (upAct) {   // my top row -> consumed by block above
            u64* p = &bufRow[rOff2 + ((size_t)blk * 2 + 0) * 128 + lx0];
            pub2(p, nv[0].x, nv[0].y, s2);
            pub2(p + 2, nv[0].z, nv[0].w, s2);
        }
        if (dnAct) {   // my bottom row -> block below
            u64* p = &bufRow[rOff2 + ((size_t)blk * 2 + 1) * 128 + lx0];
            pub2(p, nv[3].x, nv[3].y, s2);
            pub2(p + 2, nv[3].z, nv[3].w, s2);
        }
        if (lAct) {    // my left col -> left block
            u64* p = &bufCol[cOff2 + ((size_t)blk * 2 + 0) * 32 + ly0];
            pub2(p, nv[0].x, nv[1].x, s2);
            pub2(p + 2, nv[2].x, nv[3].x, s2);
        }
        if (rAct) {    // my right col -> right block
            u64* p = &bufCol[cOff2 + ((size_t)blk * 2 + 1) * 32 + ly0];
            pub2(p, nv[0].w, nv[1].w, s2);
            pub2(p + 2, nv[2].w, nv[3].w, s2);
        }

        // ---- D: interior of state t+1 into nxt; ONE barrier per step ----
#pragma unroll
        for (int k = 0; k < 4; ++k)
            *(float4*)&nxt[(ly0 + k) * 128 + lx0] = nv[k];
        __syncthreads();
        float* tmp = cur; cur = nxt; nxt = tmp;
    }
}

extern "C" void kernel_launch(void* const* d_in, const int* in_sizes, int n_in,
                              void* d_out, int out_size, void* d_ws, size_t ws_size,
                              hipStream_t stream) {
    const float* guide = (const float*)d_in[0];   // [2,3,1024,1024]
    const float* yb    = (const float*)d_in[1];   // [2,1,1024,1024]
    const float* src   = (const float*)d_in[2];   // [2,1,128,128]
    const float* mask  = (const float*)d_in[3];   // [2,1,128,128]

    float* out    = (float*)d_out;                       // y_pred [2,1,1024,1024]
    float* out_cv = out + (size_t)BB * NPIX;
    float* out_ch = out_cv + (size_t)BB * CVN;

    float* wsf = (float*)d_ws;
    float* shift = wsf;                                  // [256] slot
    float* imgA = wsf + 256;                             // init image, 2*NPIX
    float* cvp  = imgA + (size_t)BB * NPIX;              // 2*1025*1024
    float* chp  = cvp + (size_t)BB * CVPN;               // 2*1024*1024
    u64* bufRow = (u64*)(chp + (size_t)BB * NPIX);       // 2 par x 512 x 2 x 128
    u64* bufCol = bufRow + 2 * ROWPAR;                   // 2 par x 512 x 2 x 32

    setup_kernel<<<1, TPB, 0, stream>>>(src, shift);
    init_kernel<<<(BB * NPIX) / TPB, TPB, 0, stream>>>(guide, yb, shift, imgA,
                                                       out_cv, out_ch, cvp, chp);

    persist_kernel<<<NB, TPB, 0, stream>>>(imgA, out, cvp, chp, src, mask, shift,
                                           bufRow, bufCol);
}

// Round 12
// 285.969 us; speedup vs baseline: 2.3345x; 1.0798x over previous
//
#include <hip/hip_runtime.h>

// GADBase guided anisotropic diffusion on MI355X — round 12.
// R11 (308us, best) + write-combine fix + latency-overlapped polls.
// Theory: R11's ~3us/step stall is uncached-store visibility, inflated by
// partial-line write-combine (pub2 put 16B per lane at stride 32B). R12:
//  1) row publishes = ONE wave-wide global_store_dwordx4 (lane l holds
//     pixels 2l,2l+1 via 4 shuffles) -> every 64B line fully covered by a
//     single instruction -> immediate WC flush.
//  2) col publishes already cover one 64B line per wave (2 lanes x 2
//     back-to-back 16B stores, same line) — kept.
//  3) speculative polls: issue uncached dwordx4 halo loads BEFORE the
//     barrier (its mandatory vmcnt(0) drains them); check tags after, spin
//     only on miss. Protocol (tagged words, parity slots, publish-then-
//     consume proof) identical to R11.

#define BB 2
#define HH 1024
#define WW 1024
#define NPIX (HH * WW)
#define CVN (1023 * 1024)
#define CVPN (1025 * 1024)
#define SHW (128 * 128)
#define LL 0.24f
#define KK2 (0.03f * 0.03f)
#define EPSF 1e-8f
#define DEPSF 0.1f
#define NPRE 64
#define NB 512            // 2 blocks/CU on 256 CUs — co-resident
#define TPB 256

typedef unsigned long long u64;
typedef unsigned int uint4v __attribute__((ext_vector_type(4)));
#define ROWPAR ((size_t)NB * 2 * 128)   // u64s per parity plane (row buffers)
#define COLPAR ((size_t)NB * 2 * 32)

__global__ void setup_kernel(const float* __restrict__ src, float* __restrict__ shiftOut) {
    int tid = threadIdx.x;
    float m = 1e30f;
    for (int i = tid; i < BB * SHW; i += TPB) m = fminf(m, src[i]);
    for (int off = 32; off > 0; off >>= 1) m = fminf(m, __shfl_down(m, off));
    __shared__ float sm[4];
    if ((tid & 63) == 0) sm[tid >> 6] = m;
    __syncthreads();
    if (tid == 0) {
        float mm = fminf(fminf(sm[0], sm[1]), fminf(sm[2], sm[3]));
        shiftOut[0] = (mm <= DEPSF) ? DEPSF : 0.0f;
    }
}

__global__ void init_kernel(const float* __restrict__ guide, const float* __restrict__ yb,
                            const float* __restrict__ shiftPtr, float* __restrict__ img0,
                            float* __restrict__ cv_out, float* __restrict__ ch_out,
                            float* __restrict__ cvp, float* __restrict__ chp) {
    int idx = blockIdx.x * blockDim.x + threadIdx.x;
    if (idx >= BB * NPIX) return;
    int b = idx >> 20;
    int p = idx & (NPIX - 1);
    int y = p >> 10;
    int x = p & 1023;
    const float* gb = guide + (size_t)b * 3 * NPIX;
    const float* yBb = yb + (size_t)b * NPIX;
    float c0 = yBb[p];
    img0[(size_t)b * NPIX + p] = c0 + shiftPtr[0];
    // shift cancels in finite diffs -> cv/ch from raw y_bicubic.
    float* cvpb = cvp + (size_t)b * CVPN;
    float* chpb = chp + (size_t)b * NPIX;
    if (y < HH - 1) {
        float d = fabsf(gb[p + WW] - gb[p])
                + fabsf(gb[NPIX + p + WW] - gb[NPIX + p])
                + fabsf(gb[2 * NPIX + p + WW] - gb[2 * NPIX + p])
                + fabsf(yBb[p + WW] - c0);
        d *= 0.25f;
        float v = 1.0f / (1.0f + (d * d) / KK2);
        cv_out[(size_t)b * CVN + y * WW + x] = v;
        cvpb[(y + 1) * WW + x] = v;           // padded: row r holds cv[r-1]
    } else {
        cvpb[x] = 0.f;
        cvpb[1024 * WW + x] = 0.f;
    }
    if (x < WW - 1) {
        float d = fabsf(gb[p + 1] - gb[p])
                + fabsf(gb[NPIX + p + 1] - gb[NPIX + p])
                + fabsf(gb[2 * NPIX + p + 1] - gb[2 * NPIX + p])
                + fabsf(yBb[p + 1] - c0);
        d *= 0.25f;
        float v = 1.0f / (1.0f + (d * d) / KK2);
        ch_out[(size_t)b * CVN + y * 1023 + x] = v;
        chpb[y * WW + x] = v;                 // padded stride-1024, col 1023 = 0
    } else {
        chpb[y * WW + 1023] = 0.f;
    }
}

// uncached (MALL-coherent) 16B store / load
__device__ inline void ust4(void* p, uint4v q) {
    asm volatile("global_store_dwordx4 %0, %1, off sc0 sc1" :: "v"(p), "v"(q) : "memory");
}
__device__ inline uint4v uld4(const void* p) {
    uint4v r;
    asm volatile("global_load_dwordx4 %0, %1, off sc0 sc1" : "=v"(r) : "v"(p) : "memory");
    return r;
}
__device__ inline void vwait() { asm volatile("s_waitcnt vmcnt(0)" ::: "memory"); }

// 16B packed (value,tag) pair store, used for col edges (line-grouped per wave)
__device__ inline void pub2(u64* p, float v0, float v1, unsigned s) {
    uint4v q;
    q.x = __float_as_uint(v0); q.y = s;
    q.z = __float_as_uint(v1); q.w = s;
    ust4(p, q);
}
__device__ inline bool tags_ok(uint4v a, uint4v b, unsigned s) {
    return a.y == s && a.w == s && b.y == s && b.w == s;
}
__device__ inline float4 vals_of(uint4v a, uint4v b) {
    return make_float4(__uint_as_float(a.x), __uint_as_float(a.z),
                       __uint_as_float(b.x), __uint_as_float(b.z));
}
// blocking re-poll (used only on speculative miss)
__device__ inline float4 repoll(const u64* p, unsigned s) {
    for (;;) {
        uint4v a = uld4(p), b = uld4(p + 2);
        vwait();
        if (tags_ok(a, b, s)) return vals_of(a, b);
        __builtin_amdgcn_s_sleep(1);
    }
}

__launch_bounds__(TPB, 2)
__global__ void persist_kernel(const float* __restrict__ img0, float* __restrict__ out,
                               const float* __restrict__ cvp, const float* __restrict__ chp,
                               const float* __restrict__ src, const float* __restrict__ mask,
                               const float* __restrict__ shiftPtr,
                               u64* __restrict__ bufRow, u64* __restrict__ bufCol) {
    __shared__ float tile[2][32 * 128];
    int blk = blockIdx.x;
    int b = blk >> 8;
    int r = blk & 255;
    int tileY = r >> 3;          // 0..31
    int tileX = r & 7;           // 0..7
    int tid = threadIdx.x;
    int cyL = tid >> 5;          // 0..7
    int g = tid & 31;            // 0..31
    int wv = tid >> 6;           // wave 0..3
    int l0 = tid & 63;           // lane within wave
    int lx0 = g * 4;
    int ly0 = cyL * 4;
    int gx = tileX * 128 + lx0;
    int gy = tileY * 32 + ly0;

    const float* im0 = img0 + (size_t)b * NPIX;
    const float* cvpb = cvp + (size_t)b * CVPN;
    const float* chpb = chp + (size_t)b * NPIX;
    float shift = shiftPtr[0];

    // conductances resident in registers for all 64 steps
    float4 cvR[5], chR[4];
    float hmR[4];
#pragma unroll
    for (int j = 0; j < 5; ++j)
        cvR[j] = *(const float4*)(cvpb + (size_t)(gy + j) * WW + gx);
#pragma unroll
    for (int k = 0; k < 4; ++k) {
        chR[k] = *(const float4*)(chpb + (size_t)(gy + k) * WW + gx);
        hmR[k] = (gx > 0) ? chpb[(size_t)(gy + k) * WW + gx - 1] : 0.f;
    }
    int sidx = b * SHW + (tileY * 4 + (cyL >> 1)) * 128 + tileX * 16 + (g >> 1);
    float sval = src[sidx] + shift;
    bool masked = mask[sidx] < 0.5f;

    // roles: each edge's publisher thread == its poller thread (cols); rows
    // are published wave-wide but polled by the owning cyL row threads.
    bool upAct = (cyL == 0 && tileY > 0);
    bool dnAct = (cyL == 7 && tileY < 31);
    bool lAct  = (g == 0  && tileX > 0);
    bool rAct  = (g == 31 && tileX < 7);
    bool pubTop = (wv == 0 && tileY > 0);    // wave-uniform
    bool pubBot = (wv == 3 && tileY < 31);

    float* cur = &tile[0][0];
    float* nxt = &tile[1][0];

    // initial LDS interior + state-0 halo registers (0 past image edges:
    // matching conductance is 0 so the value is never used)
#pragma unroll
    for (int k = 0; k < 4; ++k)
        *(float4*)&cur[(ly0 + k) * 128 + lx0] =
            *(const float4*)(im0 + (size_t)(gy + k) * WW + gx);
    float4 z4 = make_float4(0.f, 0.f, 0.f, 0.f);
    float4 hUp = z4, hDn = z4;
    float xlR[4] = {0.f, 0.f, 0.f, 0.f}, xrR[4] = {0.f, 0.f, 0.f, 0.f};
    if (upAct) hUp = *(const float4*)(im0 + (size_t)(gy - 1) * WW + gx);
    if (dnAct) hDn = *(const float4*)(im0 + (size_t)(gy + 4) * WW + gx);
    if (lAct) {
#pragma unroll
        for (int k = 0; k < 4; ++k) xlR[k] = im0[(size_t)(gy + k) * WW + gx - 1];
    }
    if (rAct) {
#pragma unroll
        for (int k = 0; k < 4; ++k) xrR[k] = im0[(size_t)(gy + k) * WW + gx + 4];
    }
    __syncthreads();

    float4 nv[4];
    for (int t = 0; t < NPRE; ++t) {
        // ---- A: diffuse + adjust, state t -> nv = state t+1 ----
        float4 rUp = (cyL == 0) ? hUp : *(float4*)&cur[(ly0 - 1) * 128 + lx0];
        float4 rC  = *(float4*)&cur[ly0 * 128 + lx0];
        float csum = 0.f;
#pragma unroll
        for (int k = 0; k < 4; ++k) {
            float4 rDn = (k == 3 && cyL == 7) ? hDn
                       : *(float4*)&cur[(ly0 + 1 + k) * 128 + lx0];
            float4 cu = cvR[k], cd = cvR[k + 1], h4 = chR[k];
            float xl = __shfl_up(rC.w, 1);
            float xr = __shfl_down(rC.x, 1);
            float hm = hmR[k];
            if (g == 0)  xl = xlR[k];
            if (g == 31) xr = xrR[k];
            float4 a;
            a.x = rC.x + LL * (cd.x * (rDn.x - rC.x) - cu.x * (rC.x - rUp.x)
                             + h4.x * (rC.y - rC.x) - hm   * (rC.x - xl));
            a.y = rC.y + LL * (cd.y * (rDn.y - rC.y) - cu.y * (rC.y - rUp.y)
                             + h4.y * (rC.z - rC.y) - h4.x * (rC.y - rC.x));
            a.z = rC.z + LL * (cd.z * (rDn.z - rC.z) - cu.z * (rC.z - rUp.z)
                             + h4.z * (rC.w - rC.z) - h4.y * (rC.z - rC.y));
            a.w = rC.w + LL * (cd.w * (rDn.w - rC.w) - cu.w * (rC.w - rUp.w)
                             + h4.w * (xr   - rC.w) - h4.z * (rC.w - rC.z));
            nv[k] = a;
            csum += a.x + a.y + a.z + a.w;
            rUp = rC; rC = rDn;
        }
        csum += __shfl_xor(csum, 1);
        csum += __shfl_xor(csum, 32);   // 8x8 cell = lanes {tid,tid^1,tid^32,tid^33}
        float ratio = masked ? 1.0f : sval / (csum * (1.0f / 64.0f) + EPSF);

        if (t == NPRE - 1) {
            float* ob = out + (size_t)b * NPIX;
#pragma unroll
            for (int k = 0; k < 4; ++k) {
                float4 v = nv[k];
                v.x = v.x * ratio - shift; v.y = v.y * ratio - shift;
                v.z = v.z * ratio - shift; v.w = v.w * ratio - shift;
                *(float4*)(ob + (size_t)(gy + k) * WW + gx) = v;
            }
            break;
        }
#pragma unroll
        for (int k = 0; k < 4; ++k) {
            nv[k].x *= ratio; nv[k].y *= ratio; nv[k].z *= ratio; nv[k].w *= ratio;
        }

        // ---- B: publish edges tagged s2; rows = one wave-wide dwordx4 ----
        unsigned s2 = (unsigned)(t + 1);
        size_t rOff2 = (s2 & 1) ? ROWPAR : 0;
        size_t cOff2 = (s2 & 1) ? COLPAR : 0;
        if (pubTop) {   // wave 0: top row (values live in lanes 0..31 = cyL 0)
            float a = __shfl(nv[0].x, l0 >> 1), bq = __shfl(nv[0].y, l0 >> 1);
            float c = __shfl(nv[0].z, l0 >> 1), d = __shfl(nv[0].w, l0 >> 1);
            float v0 = (l0 & 1) ? c : a, v1 = (l0 & 1) ? d : bq;
            uint4v q; q.x = __float_as_uint(v0); q.y = s2;
            q.z = __float_as_uint(v1); q.w = s2;
            ust4(&bufRow[rOff2 + ((size_t)blk * 2 + 0) * 128 + 2 * l0], q);
        }
        if (pubBot) {   // wave 3: bottom row (values in local lanes 32..63 = cyL 7)
            int sl = 32 + (l0 >> 1);
            float a = __shfl(nv[3].x, sl), bq = __shfl(nv[3].y, sl);
            float c = __shfl(nv[3].z, sl), d = __shfl(nv[3].w, sl);
            float v0 = (l0 & 1) ? c : a, v1 = (l0 & 1) ? d : bq;
            uint4v q; q.x = __float_as_uint(v0); q.y = s2;
            q.z = __float_as_uint(v1); q.w = s2;
            ust4(&bufRow[rOff2 + ((size_t)blk * 2 + 1) * 128 + 2 * l0], q);
        }
        if (lAct) {     // 64B line per wave (2 lanes x 2 stores, same line)
            u64* p = &bufCol[cOff2 + ((size_t)blk * 2 + 0) * 32 + ly0];
            pub2(p, nv[0].x, nv[1].x, s2);
            pub2(p + 2, nv[2].x, nv[3].x, s2);
        }
        if (rAct) {
            u64* p = &bufCol[cOff2 + ((size_t)blk * 2 + 1) * 32 + ly0];
            pub2(p, nv[0].w, nv[1].w, s2);
            pub2(p + 2, nv[2].w, nv[3].w, s2);
        }

        // ---- C: speculative halo loads for state t+1 (complete at barrier) ----
        const u64* pUp = upAct ? &bufRow[rOff2 + (((size_t)blk - 8) * 2 + 1) * 128 + lx0] : nullptr;
        const u64* pDn = dnAct ? &bufRow[rOff2 + (((size_t)blk + 8) * 2 + 0) * 128 + lx0] : nullptr;
        const u64* pL  = lAct  ? &bufCol[cOff2 + (((size_t)blk - 1) * 2 + 1) * 32 + ly0] : nullptr;
        const u64* pR  = rAct  ? &bufCol[cOff2 + (((size_t)blk + 1) * 2 + 0) * 32 + ly0] : nullptr;
        uint4v uA, uB, dA, dB, lA, lB, rA, rB;
        if (upAct) { uA = uld4(pUp); uB = uld4(pUp + 2); }
        if (dnAct) { dA = uld4(pDn); dB = uld4(pDn + 2); }
        if (lAct)  { lA = uld4(pL);  lB = uld4(pL + 2); }
        if (rAct)  { rA = uld4(pR);  rB = uld4(pR + 2); }

        // ---- D: interior of state t+1 into nxt; ONE barrier per step ----
#pragma unroll
        for (int k = 0; k < 4; ++k)
            *(float4*)&nxt[(ly0 + k) * 128 + lx0] = nv[k];
        __syncthreads();   // also drains the speculative loads (vmcnt 0)
        vwait();

        // ---- E: resolve halos (retry only on speculative miss) ----
        if (upAct)
            hUp = tags_ok(uA, uB, s2) ? vals_of(uA, uB) : repoll(pUp, s2);
        if (dnAct)
            hDn = tags_ok(dA, dB, s2) ? vals_of(dA, dB) : repoll(pDn, s2);
        if (lAct) {
            float4 c = tags_ok(lA, lB, s2) ? vals_of(lA, lB) : repoll(pL, s2);
            xlR[0] = c.x; xlR[1] = c.y; xlR[2] = c.z; xlR[3] = c.w;
        }
        if (rAct) {
            float4 c = tags_ok(rA, rB, s2) ? vals_of(rA, rB) : repoll(pR, s2);
            xrR[0] = c.x; xrR[1] = c.y; xrR[2] = c.z; xrR[3] = c.w;
        }
        float* tmp = cur; cur = nxt; nxt = tmp;
    }
}

extern "C" void kernel_launch(void* const* d_in, const int* in_sizes, int n_in,
                              void* d_out, int out_size, void* d_ws, size_t ws_size,
                              hipStream_t stream) {
    const float* guide = (const float*)d_in[0];   // [2,3,1024,1024]
    const float* yb    = (const float*)d_in[1];   // [2,1,1024,1024]
    const float* src   = (const float*)d_in[2];   // [2,1,128,128]
    const float* mask  = (const float*)d_in[3];   // [2,1,128,128]

    float* out    = (float*)d_out;                       // y_pred [2,1,1024,1024]
    float* out_cv = out + (size_t)BB * NPIX;
    float* out_ch = out_cv + (size_t)BB * CVN;

    float* wsf = (float*)d_ws;
    float* shift = wsf;                                  // [256] slot
    float* imgA = wsf + 256;                             // init image, 2*NPIX
    float* cvp  = imgA + (size_t)BB * NPIX;              // 2*1025*1024
    float* chp  = cvp + (size_t)BB * CVPN;               // 2*1024*1024
    u64* bufRow = (u64*)(chp + (size_t)BB * NPIX);       // 2 par x 512 x 2 x 128
    u64* bufCol = bufRow + 2 * ROWPAR;                   // 2 par x 512 x 2 x 32

    setup_kernel<<<1, TPB, 0, stream>>>(src, shift);
    init_kernel<<<(BB * NPIX) / TPB, TPB, 0, stream>>>(guide, yb, shift, imgA,
                                                       out_cv, out_ch, cvp, chp);

    persist_kernel<<<NB, TPB, 0, stream>>>(imgA, out, cvp, chp, src, mask, shift,
                                           bufRow, bufCol);
}

// Round 13
// 271.950 us; speedup vs baseline: 2.4549x; 1.0516x over previous
//
#include <hip/hip_runtime.h>

// GADBase guided anisotropic diffusion on MI355X — round 13.
// R12 (286us total, persist 180us) + everything fused into ONE dispatch:
//  - shift: redundant per-block min-reduce over src (identical order per
//    block -> bitwise-identical result, no grid sync, L2-broadcast reads).
//  - conductances computed per-block straight from guide/yb into REGISTERS
//    (no cvp/chp/imgA intermediates); cv/ch output slices written here too.
//  - LDS tile + state-0 halos filled from the same yb loads.
// Main loop protocol is R12 verbatim (tagged full-line uncached publishes,
// speculative polls drained by the barrier, parity-2 slots, 1 barrier/step).

#define BB 2
#define HH 1024
#define WW 1024
#define NPIX (HH * WW)
#define CVN (1023 * 1024)
#define SHW (128 * 128)
#define LL 0.24f
#define KK2 (0.03f * 0.03f)
#define EPSF 1e-8f
#define DEPSF 0.1f
#define NPRE 64
#define NB 512            // 2 blocks/CU on 256 CUs — co-resident
#define TPB 256

typedef unsigned long long u64;
typedef unsigned int uint4v __attribute__((ext_vector_type(4)));
#define ROWPAR ((size_t)NB * 2 * 128)   // u64s per parity plane (row buffers)
#define COLPAR ((size_t)NB * 2 * 32)

// uncached (MALL-coherent) 16B store / load
__device__ inline void ust4(void* p, uint4v q) {
    asm volatile("global_store_dwordx4 %0, %1, off sc0 sc1" :: "v"(p), "v"(q) : "memory");
}
__device__ inline uint4v uld4(const void* p) {
    uint4v r;
    asm volatile("global_load_dwordx4 %0, %1, off sc0 sc1" : "=v"(r) : "v"(p) : "memory");
    return r;
}
__device__ inline void vwait() { asm volatile("s_waitcnt vmcnt(0)" ::: "memory"); }

__device__ inline void pub2(u64* p, float v0, float v1, unsigned s) {
    uint4v q;
    q.x = __float_as_uint(v0); q.y = s;
    q.z = __float_as_uint(v1); q.w = s;
    ust4(p, q);
}
__device__ inline bool tags_ok(uint4v a, uint4v b, unsigned s) {
    return a.y == s && a.w == s && b.y == s && b.w == s;
}
__device__ inline float4 vals_of(uint4v a, uint4v b) {
    return make_float4(__uint_as_float(a.x), __uint_as_float(a.z),
                       __uint_as_float(b.x), __uint_as_float(b.z));
}
__device__ inline float4 repoll(const u64* p, unsigned s) {
    for (;;) {
        uint4v a = uld4(p), b = uld4(p + 2);
        vwait();
        if (tags_ok(a, b, s)) return vals_of(a, b);
        __builtin_amdgcn_s_sleep(1);
    }
}

__device__ inline float gfun(float d) { return 1.0f / (1.0f + (d * d) / KK2); }

__launch_bounds__(TPB, 2)
__global__ void persist_kernel(const float* __restrict__ guide, const float* __restrict__ yb,
                               const float* __restrict__ src, const float* __restrict__ mask,
                               float* __restrict__ out, float* __restrict__ out_cv,
                               float* __restrict__ out_ch,
                               u64* __restrict__ bufRow, u64* __restrict__ bufCol) {
    __shared__ float tile[2][32 * 128];
    __shared__ float sm[4];
    int blk = blockIdx.x;
    int b = blk >> 8;
    int r = blk & 255;
    int tileY = r >> 3;          // 0..31
    int tileX = r & 7;           // 0..7
    int tid = threadIdx.x;
    int cyL = tid >> 5;          // 0..7
    int g = tid & 31;            // 0..31
    int wv = tid >> 6;           // wave 0..3
    int l0 = tid & 63;           // lane within wave
    int lx0 = g * 4;
    int ly0 = cyL * 4;
    int gx = tileX * 128 + lx0;
    int gy = tileY * 32 + ly0;

    // ---- phase 0: shift (redundant per-block, deterministic order) ----
    float mmin = 1e30f;
    const float4* s4 = (const float4*)src;
    for (int i = tid; i < (BB * SHW) / 4; i += TPB) {
        float4 v = s4[i];
        mmin = fminf(mmin, fminf(fminf(v.x, v.y), fminf(v.z, v.w)));
    }
    for (int off = 32; off > 0; off >>= 1) mmin = fminf(mmin, __shfl_down(mmin, off));
    if ((tid & 63) == 0) sm[tid >> 6] = mmin;
    __syncthreads();
    float mm = fminf(fminf(sm[0], sm[1]), fminf(sm[2], sm[3]));
    float shift = (mm <= DEPSF) ? DEPSF : 0.0f;

    // ---- phase 1: conductances from guide/yb (shift cancels in diffs) ----
    int ry[6];
#pragma unroll
    for (int j = 0; j < 6; ++j) {
        int y = gy - 1 + j;
        ry[j] = y < 0 ? 0 : (y > 1023 ? 1023 : y);   // clamped; OOR results forced 0
    }
    int cxl = (gx > 0) ? gx - 1 : 0;
    int cxr = (gx + 4 < 1024) ? gx + 4 : 1023;
    float4 z4 = make_float4(0.f, 0.f, 0.f, 0.f);
    float4 vd[5] = {z4, z4, z4, z4, z4};
    float4 hd[4] = {z4, z4, z4, z4};
    float hmd[4] = {0.f, 0.f, 0.f, 0.f};
    float4 imv[4], r0v = z4, r5v = z4;
    float slv[4], srv[4];
#pragma unroll
    for (int c = 0; c < 4; ++c) {
        const float* F = (c < 3) ? guide + ((size_t)b * 3 + c) * NPIX
                                 : yb + (size_t)b * NPIX;
        float4 rr[6];
#pragma unroll
        for (int j = 0; j < 6; ++j)
            rr[j] = *(const float4*)(F + (size_t)ry[j] * WW + gx);
#pragma unroll
        for (int j = 0; j < 5; ++j) {
            vd[j].x += fabsf(rr[j + 1].x - rr[j].x);
            vd[j].y += fabsf(rr[j + 1].y - rr[j].y);
            vd[j].z += fabsf(rr[j + 1].z - rr[j].z);
            vd[j].w += fabsf(rr[j + 1].w - rr[j].w);
        }
#pragma unroll
        for (int k = 0; k < 4; ++k) {
            float4 R = rr[k + 1];
            float sr = F[(size_t)ry[k + 1] * WW + cxr];
            float sl = F[(size_t)ry[k + 1] * WW + cxl];
            hd[k].x += fabsf(R.y - R.x);
            hd[k].y += fabsf(R.z - R.y);
            hd[k].z += fabsf(R.w - R.z);
            hd[k].w += fabsf(sr - R.w);
            hmd[k] += fabsf(R.x - sl);
            if (c == 3) { imv[k] = R; slv[k] = sl; srv[k] = sr; }
        }
        if (c == 3) { r0v = rr[0]; r5v = rr[5]; }
    }
    float4 cvR[5], chR[4];
    float hmR[4];
#pragma unroll
    for (int j = 0; j < 5; ++j) {
        int y = gy - 1 + j;
        if (y < 0 || y > 1022) {
            cvR[j] = z4;
        } else {
            cvR[j] = make_float4(gfun(vd[j].x * 0.25f), gfun(vd[j].y * 0.25f),
                                 gfun(vd[j].z * 0.25f), gfun(vd[j].w * 0.25f));
        }
    }
#pragma unroll
    for (int k = 0; k < 4; ++k) {
        chR[k] = make_float4(gfun(hd[k].x * 0.25f), gfun(hd[k].y * 0.25f),
                             gfun(hd[k].z * 0.25f), gfun(hd[k].w * 0.25f));
        if (gx + 3 == 1023) chR[k].w = 0.f;      // no conductance past right edge
        hmR[k] = (gx > 0) ? gfun(hmd[k] * 0.25f) : 0.f;
    }
    // cv/ch output slices for this tile
#pragma unroll
    for (int j = 1; j < 5; ++j) {
        int y = gy + j - 1;
        if (y <= 1022)
            *(float4*)(out_cv + (size_t)b * CVN + (size_t)y * WW + gx) = cvR[j];
    }
#pragma unroll
    for (int k = 0; k < 4; ++k) {
        float* base = out_ch + (size_t)b * CVN + (size_t)(gy + k) * 1023;
        base[gx + 0] = chR[k].x;                 // gx+2 <= 1022 always
        base[gx + 1] = chR[k].y;
        base[gx + 2] = chR[k].z;
        if (gx + 3 < 1023) base[gx + 3] = chR[k].w;
    }

    int sidx = b * SHW + (tileY * 4 + (cyL >> 1)) * 128 + tileX * 16 + (g >> 1);
    float sval = src[sidx] + shift;
    bool masked = mask[sidx] < 0.5f;

    bool upAct = (cyL == 0 && tileY > 0);
    bool dnAct = (cyL == 7 && tileY < 31);
    bool lAct  = (g == 0  && tileX > 0);
    bool rAct  = (g == 31 && tileX < 7);
    bool pubTop = (wv == 0 && tileY > 0);
    bool pubBot = (wv == 3 && tileY < 31);

    float* cur = &tile[0][0];
    float* nxt = &tile[1][0];

    // LDS interior (img0 = yb + shift) + state-0 halo registers
#pragma unroll
    for (int k = 0; k < 4; ++k) {
        float4 v = imv[k];
        v.x += shift; v.y += shift; v.z += shift; v.w += shift;
        *(float4*)&cur[(ly0 + k) * 128 + lx0] = v;
    }
    float4 hUp = z4, hDn = z4;
    float xlR[4] = {0.f, 0.f, 0.f, 0.f}, xrR[4] = {0.f, 0.f, 0.f, 0.f};
    if (upAct) { hUp = r0v; hUp.x += shift; hUp.y += shift; hUp.z += shift; hUp.w += shift; }
    if (dnAct) { hDn = r5v; hDn.x += shift; hDn.y += shift; hDn.z += shift; hDn.w += shift; }
    if (lAct) {
#pragma unroll
        for (int k = 0; k < 4; ++k) xlR[k] = slv[k] + shift;
    }
    if (rAct) {
#pragma unroll
        for (int k = 0; k < 4; ++k) xrR[k] = srv[k] + shift;
    }
    __syncthreads();

    float4 nv[4];
    for (int t = 0; t < NPRE; ++t) {
        // ---- A: diffuse + adjust, state t -> nv = state t+1 ----
        float4 rUp = (cyL == 0) ? hUp : *(float4*)&cur[(ly0 - 1) * 128 + lx0];
        float4 rC  = *(float4*)&cur[ly0 * 128 + lx0];
        float csum = 0.f;
#pragma unroll
        for (int k = 0; k < 4; ++k) {
            float4 rDn = (k == 3 && cyL == 7) ? hDn
                       : *(float4*)&cur[(ly0 + 1 + k) * 128 + lx0];
            float4 cu = cvR[k], cd = cvR[k + 1], h4 = chR[k];
            float xl = __shfl_up(rC.w, 1);
            float xr = __shfl_down(rC.x, 1);
            float hm = hmR[k];
            if (g == 0)  xl = xlR[k];
            if (g == 31) xr = xrR[k];
            float4 a;
            a.x = rC.x + LL * (cd.x * (rDn.x - rC.x) - cu.x * (rC.x - rUp.x)
                             + h4.x * (rC.y - rC.x) - hm   * (rC.x - xl));
            a.y = rC.y + LL * (cd.y * (rDn.y - rC.y) - cu.y * (rC.y - rUp.y)
                             + h4.y * (rC.z - rC.y) - h4.x * (rC.y - rC.x));
            a.z = rC.z + LL * (cd.z * (rDn.z - rC.z) - cu.z * (rC.z - rUp.z)
                             + h4.z * (rC.w - rC.z) - h4.y * (rC.z - rC.y));
            a.w = rC.w + LL * (cd.w * (rDn.w - rC.w) - cu.w * (rC.w - rUp.w)
                             + h4.w * (xr   - rC.w) - h4.z * (rC.w - rC.z));
            nv[k] = a;
            csum += a.x + a.y + a.z + a.w;
            rUp = rC; rC = rDn;
        }
        csum += __shfl_xor(csum, 1);
        csum += __shfl_xor(csum, 32);   // 8x8 cell = lanes {tid,tid^1,tid^32,tid^33}
        float ratio = masked ? 1.0f : sval / (csum * (1.0f / 64.0f) + EPSF);

        if (t == NPRE - 1) {
            float* ob = out + (size_t)b * NPIX;
#pragma unroll
            for (int k = 0; k < 4; ++k) {
                float4 v = nv[k];
                v.x = v.x * ratio - shift; v.y = v.y * ratio - shift;
                v.z = v.z * ratio - shift; v.w = v.w * ratio - shift;
                *(float4*)(ob + (size_t)(gy + k) * WW + gx) = v;
            }
            break;
        }
#pragma unroll
        for (int k = 0; k < 4; ++k) {
            nv[k].x *= ratio; nv[k].y *= ratio; nv[k].z *= ratio; nv[k].w *= ratio;
        }

        // ---- B: publish edges tagged s2; rows = one wave-wide dwordx4 ----
        unsigned s2 = (unsigned)(t + 1);
        size_t rOff2 = (s2 & 1) ? ROWPAR : 0;
        size_t cOff2 = (s2 & 1) ? COLPAR : 0;
        if (pubTop) {   // wave 0: top row (values live in lanes 0..31 = cyL 0)
            float a = __shfl(nv[0].x, l0 >> 1), bq = __shfl(nv[0].y, l0 >> 1);
            float c = __shfl(nv[0].z, l0 >> 1), d = __shfl(nv[0].w, l0 >> 1);
            float v0 = (l0 & 1) ? c : a, v1 = (l0 & 1) ? d : bq;
            uint4v q; q.x = __float_as_uint(v0); q.y = s2;
            q.z = __float_as_uint(v1); q.w = s2;
            ust4(&bufRow[rOff2 + ((size_t)blk * 2 + 0) * 128 + 2 * l0], q);
        }
        if (pubBot) {   // wave 3: bottom row (values in local lanes 32..63 = cyL 7)
            int sl = 32 + (l0 >> 1);
            float a = __shfl(nv[3].x, sl), bq = __shfl(nv[3].y, sl);
            float c = __shfl(nv[3].z, sl), d = __shfl(nv[3].w, sl);
            float v0 = (l0 & 1) ? c : a, v1 = (l0 & 1) ? d : bq;
            uint4v q; q.x = __float_as_uint(v0); q.y = s2;
            q.z = __float_as_uint(v1); q.w = s2;
            ust4(&bufRow[rOff2 + ((size_t)blk * 2 + 1) * 128 + 2 * l0], q);
        }
        if (lAct) {     // 64B line per wave
            u64* p = &bufCol[cOff2 + ((size_t)blk * 2 + 0) * 32 + ly0];
            pub2(p, nv[0].x, nv[1].x, s2);
            pub2(p + 2, nv[2].x, nv[3].x, s2);
        }
        if (rAct) {
            u64* p = &bufCol[cOff2 + ((size_t)blk * 2 + 1) * 32 + ly0];
            pub2(p, nv[0].w, nv[1].w, s2);
            pub2(p + 2, nv[2].w, nv[3].w, s2);
        }

        // ---- C: speculative halo loads for state t+1 (complete at barrier) ----
        const u64* pUp = upAct ? &bufRow[rOff2 + (((size_t)blk - 8) * 2 + 1) * 128 + lx0] : nullptr;
        const u64* pDn = dnAct ? &bufRow[rOff2 + (((size_t)blk + 8) * 2 + 0) * 128 + lx0] : nullptr;
        const u64* pL  = lAct  ? &bufCol[cOff2 + (((size_t)blk - 1) * 2 + 1) * 32 + ly0] : nullptr;
        const u64* pR  = rAct  ? &bufCol[cOff2 + (((size_t)blk + 1) * 2 + 0) * 32 + ly0] : nullptr;
        uint4v uA, uB, dA, dB, lA, lB, rA, rB;
        if (upAct) { uA = uld4(pUp); uB = uld4(pUp + 2); }
        if (dnAct) { dA = uld4(pDn); dB = uld4(pDn + 2); }
        if (lAct)  { lA = uld4(pL);  lB = uld4(pL + 2); }
        if (rAct)  { rA = uld4(pR);  rB = uld4(pR + 2); }

        // ---- D: interior of state t+1 into nxt; ONE barrier per step ----
#pragma unroll
        for (int k = 0; k < 4; ++k)
            *(float4*)&nxt[(ly0 + k) * 128 + lx0] = nv[k];
        __syncthreads();   // also drains the speculative loads (vmcnt 0)
        vwait();

        // ---- E: resolve halos (retry only on speculative miss) ----
        if (upAct)
            hUp = tags_ok(uA, uB, s2) ? vals_of(uA, uB) : repoll(pUp, s2);
        if (dnAct)
            hDn = tags_ok(dA, dB, s2) ? vals_of(dA, dB) : repoll(pDn, s2);
        if (lAct) {
            float4 c = tags_ok(lA, lB, s2) ? vals_of(lA, lB) : repoll(pL, s2);
            xlR[0] = c.x; xlR[1] = c.y; xlR[2] = c.z; xlR[3] = c.w;
        }
        if (rAct) {
            float4 c = tags_ok(rA, rB, s2) ? vals_of(rA, rB) : repoll(pR, s2);
            xrR[0] = c.x; xrR[1] = c.y; xrR[2] = c.z; xrR[3] = c.w;
        }
        float* tmp = cur; cur = nxt; nxt = tmp;
    }
}

extern "C" void kernel_launch(void* const* d_in, const int* in_sizes, int n_in,
                              void* d_out, int out_size, void* d_ws, size_t ws_size,
                              hipStream_t stream) {
    const float* guide = (const float*)d_in[0];   // [2,3,1024,1024]
    const float* yb    = (const float*)d_in[1];   // [2,1,1024,1024]
    const float* src   = (const float*)d_in[2];   // [2,1,128,128]
    const float* mask  = (const float*)d_in[3];   // [2,1,128,128]

    float* out    = (float*)d_out;                       // y_pred [2,1,1024,1024]
    float* out_cv = out + (size_t)BB * NPIX;             // cv [2,1,1023,1024]
    float* out_ch = out_cv + (size_t)BB * CVN;           // ch [2,1,1024,1023]

    // ws: only the halo exchange buffers. 0xAA poison cannot match any tag
    // in [1,64), so no zero-init pass is needed.
    u64* bufRow = (u64*)d_ws;                            // 2 par x 512 x 2 x 128
    u64* bufCol = bufRow + 2 * ROWPAR;                   // 2 par x 512 x 2 x 32

    persist_kernel<<<NB, TPB, 0, stream>>>(guide, yb, src, mask, out, out_cv,
                                           out_ch, bufRow, bufCol);
}